// Round 10
// baseline (25.442 us; speedup 1.0000x reference)
//
#include <hip/hip_runtime.h>

#define BATCH 32
#define DD 64
#define NN 8
#define SS 128
#define EPS_ 1e-6f
#define NTHREADS 1024
#define NK 15          // u_0..u_15; deg-15 series tail at worst c~2.8: <1e-6
#define SX2 65         // bX2 row stride (odd -> conflict-free b128 row loads)

typedef __attribute__((ext_vector_type(8))) short bf16x8;
typedef __attribute__((ext_vector_type(4))) float f32x4;

__device__ __forceinline__ unsigned short f2bf(float f) {
    unsigned u = __float_as_uint(f);
    unsigned r = u + 0x7FFFu + ((u >> 16) & 1u);   // round-to-nearest-even
    return (unsigned short)(r >> 16);
}
__device__ __forceinline__ float bf2f(unsigned short h) {
    return __uint_as_float(((unsigned)h) << 16);
}
// swizzled element index in a [64][64] bf16 matrix: 8-elem k-blocks contiguous,
// block index XORed with (row&7) so cross-row access spreads across banks
__device__ __forceinline__ int SWZ(int r, int c) {
    return r * 64 + ((((c & ~7) ^ ((r & 7) << 3))) | (c & 7));
}
// 8 contiguous bf16 of row `row`, k-block k0 (multiple of 8)
__device__ __forceinline__ bf16x8 ldrow(const short* m, int row, int k0) {
    return *(const bf16x8*)&m[row * 64 + (k0 ^ ((row & 7) << 3))];
}

#define MFMA(a, b, c) __builtin_amdgcn_mfma_f32_16x16x32_bf16((a), (b), (c), 0, 0, 0)

__launch_bounds__(NTHREADS)
__global__ void htg_kernel(const float* __restrict__ z0,
                           const float* __restrict__ time_steps,
                           const float* __restrict__ k_coeffs,
                           const float* __restrict__ r_coeffs,
                           const float* __restrict__ alpha_p,
                           const float* __restrict__ beta_p,
                           const float* __restrict__ K_bases,
                           const float* __restrict__ R_bases,
                           float* __restrict__ out,
                           int interleaved)
{
    __shared__ float bK[DD * DD];        // Ksum fp32 elem-XOR -> later xth/xtl (XT split-bf16)
    __shared__ float rt_bx2[DD * SX2];   // rtH/rtL (R^T split-bf16) -> later bX2 fp32 stride-65
    __shared__ float xhl[DD * DD];       // xh/xl (X split-bf16, SWZ rows)
    __shared__ float us[NK + 1][DD];     // Krylov vectors
    __shared__ float ub0[DD], ub1[DD];   // chain buffers (even / odd)

    short* rtH = (short*)rt_bx2;  short* rtL = rtH + DD * DD;
    float* bX2 = rt_bx2;
    short* xh  = (short*)xhl;     short* xl  = xh  + DD * DD;
    short* xth = (short*)bK;      short* xtl = xth + DD * DD;

    const int tid = threadIdx.x;
    const int b   = blockIdx.x;          // batch
    const int wv  = tid >> 6;
    const int l   = tid & 63;
    const int q   = l >> 4;              // k-subgroup 0..3
    const int cl  = l & 15;

    const float alpha = alpha_p[b];
    const float beta  = beta_p[b];
    const float dt    = time_steps[0];   // uniform grid
    float kc[NN], rc[NN];
#pragma unroll
    for (int n = 0; n < NN; ++n) {
        kc[n] = k_coeffs[b * NN + n];
        rc[n] = r_coeffs[b * NN + n];
    }
    float zv = 0.f;
    if (wv == 15) zv = z0[b * DD + l];   // seeded into us[0]/ub0 in MM1b

    // ---- Phase A: Ksum fp32 (elem-XOR) -> bK; Rsum^T split-bf16 (SWZ rows) -> rtH/rtL ----
    {
        const int i  = tid >> 4;
        const int j0 = (tid & 15) * 4;
        const int e4 = i * DD + j0;
        float4 ks = make_float4(0.f, 0.f, 0.f, 0.f);
        float4 rs = make_float4(0.f, 0.f, 0.f, 0.f);
#pragma unroll
        for (int n = 0; n < NN; ++n) {
            float4 kb = *(const float4*)&K_bases[n * DD * DD + e4];
            float4 rb = *(const float4*)&R_bases[n * DD * DD + e4];
            ks.x = fmaf(kc[n], kb.x, ks.x); ks.y = fmaf(kc[n], kb.y, ks.y);
            ks.z = fmaf(kc[n], kb.z, ks.z); ks.w = fmaf(kc[n], kb.w, ks.w);
            rs.x = fmaf(rc[n], rb.x, rs.x); rs.y = fmaf(rc[n], rb.y, rs.y);
            rs.z = fmaf(rc[n], rb.z, rs.z); rs.w = fmaf(rc[n], rb.w, rs.w);
        }
        const int c = i & 31;
        bK[i * DD + ((j0 + 0) ^ c)] = ks.x;
        bK[i * DD + ((j0 + 1) ^ c)] = ks.y;
        bK[i * DD + ((j0 + 2) ^ c)] = ks.z;
        bK[i * DD + ((j0 + 3) ^ c)] = ks.w;
        float rv[4] = {rs.x, rs.y, rs.z, rs.w};
#pragma unroll
        for (int t = 0; t < 4; ++t) {    // value (i, j0+t) -> RT[j0+t][i]
            unsigned short h  = f2bf(rv[t]);
            unsigned short lo = f2bf(rv[t] - bf2f(h));
            const int a = SWZ(j0 + t, i);
            rtH[a] = (short)h; rtL[a] = (short)lo;
        }
    }
    __syncthreads();

    // ---- MM1a (waves 0-3): RtR = R^T R via MFMA (A-frag reused over 4 tiles);
    //      X and X^T computed into registers (bK consumed here) ----
    float xs[4][4], xts[4][4];           // [tc][r], statically indexed
    if (wv < 4) {
        f32x4 accR[4] = {{0.f,0.f,0.f,0.f},{0.f,0.f,0.f,0.f},{0.f,0.f,0.f,0.f},{0.f,0.f,0.f,0.f}};
        const int rowA = 16 * wv + cl;
#pragma unroll
        for (int hK = 0; hK < 2; ++hK) {
            const int k0 = 32 * hK + 8 * q;
            bf16x8 aH = ldrow(rtH, rowA, k0), aL = ldrow(rtL, rowA, k0);
#pragma unroll
            for (int tc = 0; tc < 4; ++tc) {
                bf16x8 bH = ldrow(rtH, 16 * tc + cl, k0), bL = ldrow(rtL, 16 * tc + cl, k0);
                accR[tc] = MFMA(aH, bH, accR[tc]);
                accR[tc] = MFMA(aH, bL, accR[tc]);
                accR[tc] = MFMA(aL, bH, accR[tc]);
            }
        }
        const float da = dt * alpha, db = dt * beta;
#pragma unroll
        for (int tc = 0; tc < 4; ++tc) {
#pragma unroll
            for (int r = 0; r < 4; ++r) {
                const int i = 16 * wv + 4 * q + r;
                const int j = 16 * tc + cl;
                const float kij = bK[i * DD + (j ^ (i & 31))];
                const float kji = bK[j * DD + (i ^ (j & 31))];
                const float sk  = kij - kji;
                const float sym = -db * accR[tc][r];
                float x  = fmaf( da, sk, sym);
                float xt = fmaf(-da, sk, sym);
                if (i == j) { x += EPS_; xt += EPS_; }
                xs[tc][r] = x; xts[tc][r] = xt;
            }
        }
    }
    __syncthreads();   // all bK / rtH / rtL reads complete

    // ---- MM1b: store X -> xh/xl (fresh), X^T -> xth/xtl (over bK); seed u0 ----
    if (wv < 4) {
#pragma unroll
        for (int tc = 0; tc < 4; ++tc) {
#pragma unroll
            for (int r = 0; r < 4; ++r) {
                const int i = 16 * wv + 4 * q + r;
                const int j = 16 * tc + cl;
                const int a = SWZ(i, j);
                unsigned short h, lo;
                h = f2bf(xs[tc][r]);  lo = f2bf(xs[tc][r] - bf2f(h));
                xh[a] = (short)h;  xl[a] = (short)lo;
                h = f2bf(xts[tc][r]); lo = f2bf(xts[tc][r] - bf2f(h));
                xth[a] = (short)h; xtl[a] = (short)lo;
            }
        }
    } else if (wv == 15) {
        us[0][l] = zv;
        ub0[l]   = zv;
    }
    __syncthreads();

    // ---- MM2 (waves 0-3): X2 = X*X via MFMA (B-frags from X^T rows) -> bX2 (over rt);
    //      wave 8: u1 = X*u0 from split-bf16 X rows (fp32 accumulate) ----
    if (wv < 4) {
        f32x4 acc2[4] = {{0.f,0.f,0.f,0.f},{0.f,0.f,0.f,0.f},{0.f,0.f,0.f,0.f},{0.f,0.f,0.f,0.f}};
        const int rowA = 16 * wv + cl;
#pragma unroll
        for (int hK = 0; hK < 2; ++hK) {
            const int k0 = 32 * hK + 8 * q;
            bf16x8 aH = ldrow(xh, rowA, k0), aL = ldrow(xl, rowA, k0);
#pragma unroll
            for (int tc = 0; tc < 4; ++tc) {
                bf16x8 bH = ldrow(xth, 16 * tc + cl, k0), bL = ldrow(xtl, 16 * tc + cl, k0);
                acc2[tc] = MFMA(aH, bH, acc2[tc]);
                acc2[tc] = MFMA(aH, bL, acc2[tc]);
                acc2[tc] = MFMA(aL, bH, acc2[tc]);
            }
        }
#pragma unroll
        for (int tc = 0; tc < 4; ++tc) {
#pragma unroll
            for (int r = 0; r < 4; ++r) {
                const int i = 16 * wv + 4 * q + r;
                const int j = 16 * tc + cl;
                bX2[i * SX2 + j] = acc2[tc][r];
            }
        }
    } else if (wv == 8) {
        // u1[l] = sum_c X[l][c] * u0[c]
        float acc = 0.f;
#pragma unroll
        for (int k0 = 0; k0 < DD; k0 += 8) {
            bf16x8 h8 = ldrow(xh, l, k0);
            bf16x8 l8 = ldrow(xl, l, k0);
            float4 v0 = *(const float4*)&us[0][k0];
            float4 v1 = *(const float4*)&us[0][k0 + 4];
            acc = fmaf(bf2f((unsigned short)h8[0]) + bf2f((unsigned short)l8[0]), v0.x, acc);
            acc = fmaf(bf2f((unsigned short)h8[1]) + bf2f((unsigned short)l8[1]), v0.y, acc);
            acc = fmaf(bf2f((unsigned short)h8[2]) + bf2f((unsigned short)l8[2]), v0.z, acc);
            acc = fmaf(bf2f((unsigned short)h8[3]) + bf2f((unsigned short)l8[3]), v0.w, acc);
            acc = fmaf(bf2f((unsigned short)h8[4]) + bf2f((unsigned short)l8[4]), v1.x, acc);
            acc = fmaf(bf2f((unsigned short)h8[5]) + bf2f((unsigned short)l8[5]), v1.y, acc);
            acc = fmaf(bf2f((unsigned short)h8[6]) + bf2f((unsigned short)l8[6]), v1.z, acc);
            acc = fmaf(bf2f((unsigned short)h8[7]) + bf2f((unsigned short)l8[7]), v1.w, acc);
        }
        us[1][l] = acc;
        ub1[l]   = acc;
    }
    __syncthreads();

    // ---- Chain (waves 0,1; barrier-free): u_{k+2} = X2 * u_k, two parallel strands ----
    if (wv < 2) {
        float xr[DD];                    // row l of X2 (compile-time indexed)
#pragma unroll
        for (int c = 0; c < DD; c += 4) {
            float4 t4 = *(const float4*)&bX2[l * SX2 + c];
            xr[c + 0] = t4.x; xr[c + 1] = t4.y; xr[c + 2] = t4.z; xr[c + 3] = t4.w;
        }
        float* myub = (wv == 0) ? ub0 : ub1;
        asm volatile("s_waitcnt lgkmcnt(0)" ::: "memory");
        for (int it = 0; it < 7; ++it) {
            const int k = 2 + wv + 2 * it;
            float a0 = 0.f, a1 = 0.f, a2 = 0.f, a3 = 0.f;
#pragma unroll
            for (int c = 0; c < DD; c += 16) {
                float4 v0 = *(const float4*)&myub[c + 0];
                float4 v1 = *(const float4*)&myub[c + 4];
                float4 v2 = *(const float4*)&myub[c + 8];
                float4 v3 = *(const float4*)&myub[c + 12];
                a0 = fmaf(xr[c + 0], v0.x, a0); a0 = fmaf(xr[c + 1], v0.y, a0);
                a0 = fmaf(xr[c + 2], v0.z, a0); a0 = fmaf(xr[c + 3], v0.w, a0);
                a1 = fmaf(xr[c + 4], v1.x, a1); a1 = fmaf(xr[c + 5], v1.y, a1);
                a1 = fmaf(xr[c + 6], v1.z, a1); a1 = fmaf(xr[c + 7], v1.w, a1);
                a2 = fmaf(xr[c + 8], v2.x, a2); a2 = fmaf(xr[c + 9], v2.y, a2);
                a2 = fmaf(xr[c + 10], v2.z, a2); a2 = fmaf(xr[c + 11], v2.w, a2);
                a3 = fmaf(xr[c + 12], v3.x, a3); a3 = fmaf(xr[c + 13], v3.y, a3);
                a3 = fmaf(xr[c + 14], v3.z, a3); a3 = fmaf(xr[c + 15], v3.w, a3);
            }
            const float un = (a0 + a1) + (a2 + a3);
            myub[l]  = un;
            us[k][l] = un;
            asm volatile("s_waitcnt lgkmcnt(0)" ::: "memory");
        }
    }
    __syncthreads();

    // ---- Output (Horner): z_s[i] = sum_k t^k * (u_k[i]/k!), t = s+1 ----
    {
        const int i  = tid & 63;
        const int sb = tid >> 6;         // 0..15
        const float INVF[NK + 1] = {
            1.f, 1.f, 0.5f, 1.66666667e-1f, 4.16666667e-2f, 8.33333333e-3f,
            1.38888889e-3f, 1.98412698e-4f, 2.48015873e-5f, 2.75573192e-6f,
            2.75573192e-7f, 2.50521084e-8f, 2.08767570e-9f, 1.60590438e-10f,
            1.14707456e-11f, 7.64716373e-13f };
        float w[NK + 1];
#pragma unroll
        for (int k = 0; k <= NK; ++k) w[k] = us[k][i] * INVF[k];
#pragma unroll
        for (int r = 0; r < 8; ++r) {
            const int s = sb + 16 * r;
            const float t = (float)(s + 1);
            float acc = w[NK];
#pragma unroll
            for (int k = NK - 1; k >= 0; --k) acc = fmaf(acc, t, w[k]);
            const size_t oi = ((size_t)(b * SS + s)) * DD + i;
            if (interleaved) ((float2*)out)[oi] = make_float2(acc, 0.f);
            else             out[oi] = acc;
        }
    }
}

extern "C" void kernel_launch(void* const* d_in, const int* in_sizes, int n_in,
                              void* d_out, int out_size, void* d_ws, size_t ws_size,
                              hipStream_t stream) {
    const float* z0         = (const float*)d_in[0];
    const float* time_steps = (const float*)d_in[1];
    const float* k_coeffs   = (const float*)d_in[2];
    const float* r_coeffs   = (const float*)d_in[3];
    const float* alpha      = (const float*)d_in[4];
    const float* beta       = (const float*)d_in[5];
    const float* K_bases    = (const float*)d_in[6];
    const float* R_bases    = (const float*)d_in[7];
    float* out = (float*)d_out;

    const int n_z = BATCH * SS * DD;
    const int interleaved = (out_size >= 2 * n_z) ? 1 : 0;

    htg_kernel<<<dim3(BATCH), dim3(NTHREADS), 0, stream>>>(
        z0, time_steps, k_coeffs, r_coeffs, alpha, beta, K_bases, R_bases,
        out, interleaved);
}

// Round 11
// 24.740 us; speedup vs baseline: 1.0284x; 1.0284x over previous
//
#include <hip/hip_runtime.h>

#define BATCH 32
#define DD 64
#define NN 8
#define SS 128
#define EPS_ 1e-6f
#define NTHREADS 1024
#define NK 15          // u_0..u_15; deg-15 series tail at worst c~2.8: <1e-6
#define SX2 65         // bX2 row stride (65%32==1 -> conflict-free per-lane row loads)

typedef __attribute__((ext_vector_type(8))) short bf16x8;
typedef __attribute__((ext_vector_type(4))) float f32x4;

__device__ __forceinline__ unsigned short f2bf(float f) {
    unsigned u = __float_as_uint(f);
    unsigned r = u + 0x7FFFu + ((u >> 16) & 1u);   // round-to-nearest-even
    return (unsigned short)(r >> 16);
}
__device__ __forceinline__ float bf2f(unsigned short h) {
    return __uint_as_float(((unsigned)h) << 16);
}
// swizzled element index in a [64][64] bf16 matrix: 8-elem k-blocks contiguous,
// block index XORed with (row&7) so cross-row access spreads across banks
__device__ __forceinline__ int SWZ(int r, int c) {
    return r * 64 + ((((c & ~7) ^ ((r & 7) << 3))) | (c & 7));
}
// 8 contiguous bf16 of row `row`, k-block k0 (multiple of 8)
__device__ __forceinline__ bf16x8 ldrow(const short* m, int row, int k0) {
    return *(const bf16x8*)&m[row * 64 + (k0 ^ ((row & 7) << 3))];
}

#define MFMA(a, b, c) __builtin_amdgcn_mfma_f32_16x16x32_bf16((a), (b), (c), 0, 0, 0)

__launch_bounds__(NTHREADS)
__global__ void htg_kernel(const float* __restrict__ z0,
                           const float* __restrict__ time_steps,
                           const float* __restrict__ k_coeffs,
                           const float* __restrict__ r_coeffs,
                           const float* __restrict__ alpha_p,
                           const float* __restrict__ beta_p,
                           const float* __restrict__ K_bases,
                           const float* __restrict__ R_bases,
                           float* __restrict__ out,
                           int interleaved)
{
    __shared__ float bK[DD * DD];        // Ksum fp32 elem-XOR -> xth/xtl (X^T split-bf16)
    __shared__ float rt_bx2[DD * SX2];   // rtH/rtL (R^T split-bf16) -> bX2 fp32 stride-65
    __shared__ float xhl[DD * DD];       // xh/xl (X split-bf16, SWZ rows)
    __shared__ float us[NK + 1][DD];     // Krylov vectors
    __shared__ float ub0[DD], ub1[DD];   // strand buffers

    short* rtH = (short*)rt_bx2;  short* rtL = rtH + DD * DD;
    float* bX2 = rt_bx2;
    short* xh  = (short*)xhl;     short* xl  = xh  + DD * DD;
    short* xth = (short*)bK;      short* xtl = xth + DD * DD;

    const int tid = threadIdx.x;
    const int b   = blockIdx.x;          // batch
    const int wv  = tid >> 6;
    const int l   = tid & 63;
    const int tr  = wv >> 2, tc = wv & 3;
    const int q   = l >> 4;              // k-subgroup 0..3
    const int cl  = l & 15;

    const float alpha = alpha_p[b];
    const float beta  = beta_p[b];
    const float dt    = time_steps[0];   // uniform grid
    float kc[NN], rc[NN];
#pragma unroll
    for (int n = 0; n < NN; ++n) {
        kc[n] = k_coeffs[b * NN + n];
        rc[n] = r_coeffs[b * NN + n];
    }
    float zv = 0.f;
    if (wv == 15) zv = z0[b * DD + l];   // seeded into us[0]/ub0 in MM1b

    // ---- Phase A: Ksum fp32 (elem-XOR) -> bK; Rsum^T split-bf16 (SWZ rows) -> rtH/rtL ----
    {
        const int i  = tid >> 4;
        const int j0 = (tid & 15) * 4;
        const int e4 = i * DD + j0;
        float4 ks = make_float4(0.f, 0.f, 0.f, 0.f);
        float4 rs = make_float4(0.f, 0.f, 0.f, 0.f);
#pragma unroll
        for (int n = 0; n < NN; ++n) {
            float4 kb = *(const float4*)&K_bases[n * DD * DD + e4];
            float4 rb = *(const float4*)&R_bases[n * DD * DD + e4];
            ks.x = fmaf(kc[n], kb.x, ks.x); ks.y = fmaf(kc[n], kb.y, ks.y);
            ks.z = fmaf(kc[n], kb.z, ks.z); ks.w = fmaf(kc[n], kb.w, ks.w);
            rs.x = fmaf(rc[n], rb.x, rs.x); rs.y = fmaf(rc[n], rb.y, rs.y);
            rs.z = fmaf(rc[n], rb.z, rs.z); rs.w = fmaf(rc[n], rb.w, rs.w);
        }
        const int c = i & 31;
        bK[i * DD + ((j0 + 0) ^ c)] = ks.x;
        bK[i * DD + ((j0 + 1) ^ c)] = ks.y;
        bK[i * DD + ((j0 + 2) ^ c)] = ks.z;
        bK[i * DD + ((j0 + 3) ^ c)] = ks.w;
        float rv[4] = {rs.x, rs.y, rs.z, rs.w};
#pragma unroll
        for (int t = 0; t < 4; ++t) {    // value (i, j0+t) -> RT[j0+t][i]
            unsigned short h  = f2bf(rv[t]);
            unsigned short lo = f2bf(rv[t] - bf2f(h));
            const int a = SWZ(j0 + t, i);
            rtH[a] = (short)h; rtL[a] = (short)lo;
        }
    }
    __syncthreads();

    // ---- MM1a (16 waves, 1 tile each): RtR via MFMA; X and X^T into registers ----
    float xs[4], xts[4];
    {
        f32x4 accR = {0.f, 0.f, 0.f, 0.f};
        const int rowA = 16 * tr + cl;
        const int rowB = 16 * tc + cl;   // B[k][j] = RT[j][k] -> row j of RT
#pragma unroll
        for (int hK = 0; hK < 2; ++hK) {
            const int k0 = 32 * hK + 8 * q;
            bf16x8 aH = ldrow(rtH, rowA, k0), aL = ldrow(rtL, rowA, k0);
            bf16x8 bH = ldrow(rtH, rowB, k0), bL = ldrow(rtL, rowB, k0);
            accR = MFMA(aH, bH, accR);
            accR = MFMA(aH, bL, accR);
            accR = MFMA(aL, bH, accR);
        }
        const float da = dt * alpha, db = dt * beta;
#pragma unroll
        for (int r = 0; r < 4; ++r) {
            const int i = 16 * tr + 4 * q + r;
            const int j = 16 * tc + cl;
            const float kij = bK[i * DD + (j ^ (i & 31))];
            const float kji = bK[j * DD + (i ^ (j & 31))];
            const float sk  = kij - kji;
            const float sym = -db * accR[r];
            float x  = fmaf( da, sk, sym);
            float xt = fmaf(-da, sk, sym);
            if (i == j) { x += EPS_; xt += EPS_; }
            xs[r] = x; xts[r] = xt;
        }
    }
    __syncthreads();   // all bK / rtH / rtL reads complete

    // ---- MM1b: store X -> xh/xl (fresh), X^T -> xth/xtl (over bK); seed u0 ----
    {
#pragma unroll
        for (int r = 0; r < 4; ++r) {
            const int i = 16 * tr + 4 * q + r;
            const int j = 16 * tc + cl;
            const int a = SWZ(i, j);
            unsigned short h, lo;
            h = f2bf(xs[r]);  lo = f2bf(xs[r] - bf2f(h));
            xh[a] = (short)h;  xl[a] = (short)lo;
            h = f2bf(xts[r]); lo = f2bf(xts[r] - bf2f(h));
            xth[a] = (short)h; xtl[a] = (short)lo;
        }
        if (wv == 15) { us[0][l] = zv; ub0[l] = zv; }
    }
    __syncthreads();

    // ---- MM2 (16 waves, 1 tile each): X2 = X*X via MFMA (B-frags from X^T rows) -> bX2 ----
    {
        f32x4 acc2 = {0.f, 0.f, 0.f, 0.f};
        const int rowA = 16 * tr + cl;
        const int rowB = 16 * tc + cl;
#pragma unroll
        for (int hK = 0; hK < 2; ++hK) {
            const int k0 = 32 * hK + 8 * q;
            bf16x8 aH = ldrow(xh, rowA, k0), aL = ldrow(xl, rowA, k0);
            bf16x8 bH = ldrow(xth, rowB, k0), bL = ldrow(xtl, rowB, k0);
            acc2 = MFMA(aH, bH, acc2);
            acc2 = MFMA(aH, bL, acc2);
            acc2 = MFMA(aL, bH, acc2);
        }
#pragma unroll
        for (int r = 0; r < 4; ++r) {
            const int i = 16 * tr + 4 * q + r;
            const int j = 16 * tc + cl;
            bX2[i * SX2 + j] = acc2[r];
        }
    }
    __syncthreads();

    // ---- Chain (waves 0,1; barrier-free): strand0: u2,u4,..,u14; strand1: u1 then u3,..,u15 ----
    if (wv < 2) {
        float xr[DD];                    // row l of X2 (compile-time indexed)
#pragma unroll
        for (int c = 0; c < DD; c += 4) {
            float4 t4 = *(const float4*)&bX2[l * SX2 + c];
            xr[c + 0] = t4.x; xr[c + 1] = t4.y; xr[c + 2] = t4.z; xr[c + 3] = t4.w;
        }
        float* myub = (wv == 0) ? ub0 : ub1;
        if (wv == 1) {
            // u1[l] = sum_c X[l][c] * u0[c]  (split-bf16 X rows, fp32 accumulate)
            float acc = 0.f;
#pragma unroll
            for (int k0 = 0; k0 < DD; k0 += 8) {
                bf16x8 h8 = ldrow(xh, l, k0);
                bf16x8 l8 = ldrow(xl, l, k0);
                float4 v0 = *(const float4*)&us[0][k0];
                float4 v1 = *(const float4*)&us[0][k0 + 4];
                acc = fmaf(bf2f((unsigned short)h8[0]) + bf2f((unsigned short)l8[0]), v0.x, acc);
                acc = fmaf(bf2f((unsigned short)h8[1]) + bf2f((unsigned short)l8[1]), v0.y, acc);
                acc = fmaf(bf2f((unsigned short)h8[2]) + bf2f((unsigned short)l8[2]), v0.z, acc);
                acc = fmaf(bf2f((unsigned short)h8[3]) + bf2f((unsigned short)l8[3]), v0.w, acc);
                acc = fmaf(bf2f((unsigned short)h8[4]) + bf2f((unsigned short)l8[4]), v1.x, acc);
                acc = fmaf(bf2f((unsigned short)h8[5]) + bf2f((unsigned short)l8[5]), v1.y, acc);
                acc = fmaf(bf2f((unsigned short)h8[6]) + bf2f((unsigned short)l8[6]), v1.z, acc);
                acc = fmaf(bf2f((unsigned short)h8[7]) + bf2f((unsigned short)l8[7]), v1.w, acc);
            }
            us[1][l] = acc;
            myub[l]  = acc;
        }
        asm volatile("s_waitcnt lgkmcnt(0)" ::: "memory");
        for (int it = 0; it < 7; ++it) {
            const int k = 2 + wv + 2 * it;
            float a0 = 0.f, a1 = 0.f, a2 = 0.f, a3 = 0.f;
#pragma unroll
            for (int c = 0; c < DD; c += 16) {
                float4 v0 = *(const float4*)&myub[c + 0];
                float4 v1 = *(const float4*)&myub[c + 4];
                float4 v2 = *(const float4*)&myub[c + 8];
                float4 v3 = *(const float4*)&myub[c + 12];
                a0 = fmaf(xr[c + 0], v0.x, a0); a0 = fmaf(xr[c + 1], v0.y, a0);
                a0 = fmaf(xr[c + 2], v0.z, a0); a0 = fmaf(xr[c + 3], v0.w, a0);
                a1 = fmaf(xr[c + 4], v1.x, a1); a1 = fmaf(xr[c + 5], v1.y, a1);
                a1 = fmaf(xr[c + 6], v1.z, a1); a1 = fmaf(xr[c + 7], v1.w, a1);
                a2 = fmaf(xr[c + 8], v2.x, a2); a2 = fmaf(xr[c + 9], v2.y, a2);
                a2 = fmaf(xr[c + 10], v2.z, a2); a2 = fmaf(xr[c + 11], v2.w, a2);
                a3 = fmaf(xr[c + 12], v3.x, a3); a3 = fmaf(xr[c + 13], v3.y, a3);
                a3 = fmaf(xr[c + 14], v3.z, a3); a3 = fmaf(xr[c + 15], v3.w, a3);
            }
            const float un = (a0 + a1) + (a2 + a3);
            myub[l]  = un;
            us[k][l] = un;
            asm volatile("s_waitcnt lgkmcnt(0)" ::: "memory");
        }
    }
    __syncthreads();

    // ---- Output (Horner): z_s[i] = sum_k t^k * (u_k[i]/k!), t = s+1 ----
    {
        const int i  = tid & 63;
        const int sb = tid >> 6;         // 0..15
        const float INVF[NK + 1] = {
            1.f, 1.f, 0.5f, 1.66666667e-1f, 4.16666667e-2f, 8.33333333e-3f,
            1.38888889e-3f, 1.98412698e-4f, 2.48015873e-5f, 2.75573192e-6f,
            2.75573192e-7f, 2.50521084e-8f, 2.08767570e-9f, 1.60590438e-10f,
            1.14707456e-11f, 7.64716373e-13f };
        float w[NK + 1];
#pragma unroll
        for (int k = 0; k <= NK; ++k) w[k] = us[k][i] * INVF[k];
#pragma unroll
        for (int r = 0; r < 8; ++r) {
            const int s = sb + 16 * r;
            const float t = (float)(s + 1);
            float acc = w[NK];
#pragma unroll
            for (int k = NK - 1; k >= 0; --k) acc = fmaf(acc, t, w[k]);
            const size_t oi = ((size_t)(b * SS + s)) * DD + i;
            if (interleaved) ((float2*)out)[oi] = make_float2(acc, 0.f);
            else             out[oi] = acc;
        }
    }
}

extern "C" void kernel_launch(void* const* d_in, const int* in_sizes, int n_in,
                              void* d_out, int out_size, void* d_ws, size_t ws_size,
                              hipStream_t stream) {
    const float* z0         = (const float*)d_in[0];
    const float* time_steps = (const float*)d_in[1];
    const float* k_coeffs   = (const float*)d_in[2];
    const float* r_coeffs   = (const float*)d_in[3];
    const float* alpha      = (const float*)d_in[4];
    const float* beta       = (const float*)d_in[5];
    const float* K_bases    = (const float*)d_in[6];
    const float* R_bases    = (const float*)d_in[7];
    float* out = (float*)d_out;

    const int n_z = BATCH * SS * DD;
    const int interleaved = (out_size >= 2 * n_z) ? 1 : 0;

    htg_kernel<<<dim3(BATCH), dim3(NTHREADS), 0, stream>>>(
        z0, time_steps, k_coeffs, r_coeffs, alpha, beta, K_bases, R_bases,
        out, interleaved);
}

// Round 12
// 14.634 us; speedup vs baseline: 1.7385x; 1.6906x over previous
//
#include <hip/hip_runtime.h>

#define BATCH 32
#define DD 64
#define NN 8
#define SS 128
#define EPS_ 1e-6f
#define NTHREADS 1024
#define NK 12          // u_0..u_12; deg-12 tail at worst c~2.8: 2.8^13/13! ~ 1e-4, typ c~2.1: 2e-6
#define SX 65          // bX row stride in floats (odd mod 32 -> bank-spread rows)

typedef __attribute__((ext_vector_type(8))) short bf16x8;
typedef __attribute__((ext_vector_type(4))) float f32x4;

__device__ __forceinline__ unsigned short f2bf(float f) {
    unsigned u = __float_as_uint(f);
    unsigned r = u + 0x7FFFu + ((u >> 16) & 1u);   // round-to-nearest-even
    return (unsigned short)(r >> 16);
}
__device__ __forceinline__ float bf2f(unsigned short h) {
    return __uint_as_float(((unsigned)h) << 16);
}
// swizzled element index in a [64][64] bf16 matrix: 8-elem k-blocks contiguous,
// block index XORed with (row&7) so cross-row access spreads across banks
__device__ __forceinline__ int SWZ(int r, int c) {
    return r * 64 + ((((c & ~7) ^ ((r & 7) << 3))) | (c & 7));
}
// 8 contiguous bf16 of row `row`, k-block k0 (multiple of 8)
__device__ __forceinline__ bf16x8 ldrow(const short* m, int row, int k0) {
    return *(const bf16x8*)&m[row * 64 + (k0 ^ ((row & 7) << 3))];
}

#define MFMA(a, b, c) __builtin_amdgcn_mfma_f32_16x16x32_bf16((a), (b), (c), 0, 0, 0)

__launch_bounds__(NTHREADS)
__global__ void htg_kernel(const float* __restrict__ z0,
                           const float* __restrict__ time_steps,
                           const float* __restrict__ k_coeffs,
                           const float* __restrict__ r_coeffs,
                           const float* __restrict__ alpha_p,
                           const float* __restrict__ beta_p,
                           const float* __restrict__ K_bases,
                           const float* __restrict__ R_bases,
                           float* __restrict__ out,
                           int interleaved)
{
    __shared__ float bK[DD * DD];        // Ksum fp32, elem-XOR layout
    __shared__ short rtH[DD * DD];       // Rsum^T bf16 high (SWZ rows)
    __shared__ short rtL[DD * DD];       // Rsum^T bf16 low residual
    __shared__ float bX[DD * SX];        // X fp32, stride-65 rows
    __shared__ float us[NK + 1][DD];     // Krylov vectors u_k = X^k z0

    const int tid = threadIdx.x;
    const int b   = blockIdx.x;          // batch
    const int wv  = tid >> 6;            // wave 0..15 -> 16x16 tile (tr, tc)
    const int l   = tid & 63;
    const int tr  = wv >> 2, tc = wv & 3;
    const int q   = l >> 4;              // k-subgroup 0..3
    const int cl  = l & 15;

    const float alpha = alpha_p[b];
    const float beta  = beta_p[b];
    const float dt    = time_steps[0];   // uniform grid
    float kc[NN], rc[NN];
#pragma unroll
    for (int n = 0; n < NN; ++n) {
        kc[n] = k_coeffs[b * NN + n];
        rc[n] = r_coeffs[b * NN + n];
    }
    float zv = 0.f;
    if (wv == 0) zv = z0[b * DD + l];    // latency hides under Phase A

    // ---- Phase A: Ksum fp32 (elem-XOR) -> bK; Rsum^T split-bf16 (SWZ rows) -> rtH/rtL ----
    {
        const int i  = tid >> 4;
        const int j0 = (tid & 15) * 4;
        const int e4 = i * DD + j0;
        float4 ks = make_float4(0.f, 0.f, 0.f, 0.f);
        float4 rs = make_float4(0.f, 0.f, 0.f, 0.f);
#pragma unroll
        for (int n = 0; n < NN; ++n) {
            float4 kb = *(const float4*)&K_bases[n * DD * DD + e4];
            float4 rb = *(const float4*)&R_bases[n * DD * DD + e4];
            ks.x = fmaf(kc[n], kb.x, ks.x); ks.y = fmaf(kc[n], kb.y, ks.y);
            ks.z = fmaf(kc[n], kb.z, ks.z); ks.w = fmaf(kc[n], kb.w, ks.w);
            rs.x = fmaf(rc[n], rb.x, rs.x); rs.y = fmaf(rc[n], rb.y, rs.y);
            rs.z = fmaf(rc[n], rb.z, rs.z); rs.w = fmaf(rc[n], rb.w, rs.w);
        }
        const int c = i & 31;
        bK[i * DD + ((j0 + 0) ^ c)] = ks.x;
        bK[i * DD + ((j0 + 1) ^ c)] = ks.y;
        bK[i * DD + ((j0 + 2) ^ c)] = ks.z;
        bK[i * DD + ((j0 + 3) ^ c)] = ks.w;
        // transposed store: value (i, j0+t) -> RT[j0+t][i]
        float rv[4] = {rs.x, rs.y, rs.z, rs.w};
#pragma unroll
        for (int t = 0; t < 4; ++t) {
            unsigned short h  = f2bf(rv[t]);
            unsigned short lo = f2bf(rv[t] - bf2f(h));
            const int a = SWZ(j0 + t, i);
            rtH[a] = (short)h; rtL[a] = (short)lo;
        }
    }
    __syncthreads();

    // ---- MM1 (MFMA): RtR[i][j] = sum_k RT[i][k]*RT[j][k]; all fragments b128 row reads.
    //      X = dt*(alpha*(K-K^T) - beta*RtR) + eps*I -> bX fp32 (stride 65) ----
    {
        f32x4 accR = {0.f, 0.f, 0.f, 0.f};
        const int rowA = 16 * tr + cl;
        const int rowB = 16 * tc + cl;   // B[k][j] = RT[j][k] -> row j of RT
#pragma unroll
        for (int hK = 0; hK < 2; ++hK) {
            const int k0 = 32 * hK + 8 * q;
            bf16x8 aH = ldrow(rtH, rowA, k0), aL = ldrow(rtL, rowA, k0);
            bf16x8 bH = ldrow(rtH, rowB, k0), bL = ldrow(rtL, rowB, k0);
            accR = MFMA(aH, bH, accR);
            accR = MFMA(aH, bL, accR);
            accR = MFMA(aL, bH, accR);
        }
#pragma unroll
        for (int r = 0; r < 4; ++r) {
            const int i = 16 * tr + 4 * q + r;
            const int j = 16 * tc + cl;
            const float kij = bK[i * DD + (j ^ (i & 31))];
            const float kji = bK[j * DD + (i ^ (j & 31))];
            float x = dt * (alpha * (kij - kji) - beta * accR[r]);
            if (i == j) x += EPS_;
            bX[i * SX + j] = x;
        }
    }
    __syncthreads();

    // ---- Chain (wave 0 only, barrier-free): u_k = X*u_{k-1}, k=1..NK ----
    if (wv == 0) {
        float xr[DD];                    // row l of X in registers (compile-time indexed)
#pragma unroll
        for (int c = 0; c < DD; c += 4) {
            float4 t4 = *(const float4*)&bX[l * SX + c];
            xr[c + 0] = t4.x; xr[c + 1] = t4.y; xr[c + 2] = t4.z; xr[c + 3] = t4.w;
        }
        us[0][l] = zv;
        asm volatile("s_waitcnt lgkmcnt(0)" ::: "memory");
        for (int k = 1; k <= NK; ++k) {
            const float* up = us[k - 1];
            float a0 = 0.f, a1 = 0.f, a2 = 0.f, a3 = 0.f;
#pragma unroll
            for (int c = 0; c < DD; c += 16) {
                float4 v0 = *(const float4*)&up[c + 0];
                float4 v1 = *(const float4*)&up[c + 4];
                float4 v2 = *(const float4*)&up[c + 8];
                float4 v3 = *(const float4*)&up[c + 12];
                a0 = fmaf(xr[c + 0], v0.x, a0); a0 = fmaf(xr[c + 1], v0.y, a0);
                a0 = fmaf(xr[c + 2], v0.z, a0); a0 = fmaf(xr[c + 3], v0.w, a0);
                a1 = fmaf(xr[c + 4], v1.x, a1); a1 = fmaf(xr[c + 5], v1.y, a1);
                a1 = fmaf(xr[c + 6], v1.z, a1); a1 = fmaf(xr[c + 7], v1.w, a1);
                a2 = fmaf(xr[c + 8], v2.x, a2); a2 = fmaf(xr[c + 9], v2.y, a2);
                a2 = fmaf(xr[c + 10], v2.z, a2); a2 = fmaf(xr[c + 11], v2.w, a2);
                a3 = fmaf(xr[c + 12], v3.x, a3); a3 = fmaf(xr[c + 13], v3.y, a3);
                a3 = fmaf(xr[c + 14], v3.z, a3); a3 = fmaf(xr[c + 15], v3.w, a3);
            }
            us[k][l] = (a0 + a1) + (a2 + a3);
            asm volatile("s_waitcnt lgkmcnt(0)" ::: "memory");  // write visible before next reads
        }
    }
    __syncthreads();

    // ---- Output (Horner): z_s[i] = sum_k t^k * (u_k[i]/k!), t = s+1 ----
    {
        const int i  = tid & 63;
        const int sb = tid >> 6;         // 0..15
        const float INVF[NK + 1] = {
            1.f, 1.f, 0.5f, 1.66666667e-1f, 4.16666667e-2f, 8.33333333e-3f,
            1.38888889e-3f, 1.98412698e-4f, 2.48015873e-5f, 2.75573192e-6f,
            2.75573192e-7f, 2.50521084e-8f, 2.08767570e-9f };
        float w[NK + 1];
#pragma unroll
        for (int k = 0; k <= NK; ++k) w[k] = us[k][i] * INVF[k];
#pragma unroll
        for (int r = 0; r < 8; ++r) {
            const int s = sb + 16 * r;
            const float t = (float)(s + 1);
            float acc = w[NK];
#pragma unroll
            for (int k = NK - 1; k >= 0; --k) acc = fmaf(acc, t, w[k]);
            const size_t oi = ((size_t)(b * SS + s)) * DD + i;
            if (interleaved) ((float2*)out)[oi] = make_float2(acc, 0.f);
            else             out[oi] = acc;
        }
    }
}

extern "C" void kernel_launch(void* const* d_in, const int* in_sizes, int n_in,
                              void* d_out, int out_size, void* d_ws, size_t ws_size,
                              hipStream_t stream) {
    const float* z0         = (const float*)d_in[0];
    const float* time_steps = (const float*)d_in[1];
    const float* k_coeffs   = (const float*)d_in[2];
    const float* r_coeffs   = (const float*)d_in[3];
    const float* alpha      = (const float*)d_in[4];
    const float* beta       = (const float*)d_in[5];
    const float* K_bases    = (const float*)d_in[6];
    const float* R_bases    = (const float*)d_in[7];
    float* out = (float*)d_out;

    const int n_z = BATCH * SS * DD;
    const int interleaved = (out_size >= 2 * n_z) ? 1 : 0;

    htg_kernel<<<dim3(BATCH), dim3(NTHREADS), 0, stream>>>(
        z0, time_steps, k_coeffs, r_coeffs, alpha, beta, K_bases, R_bases,
        out, interleaved);
}

// Round 13
// 12.968 us; speedup vs baseline: 1.9618x; 1.1285x over previous
//
#include <hip/hip_runtime.h>

#define BATCH 32
#define DD 64
#define NN 8
#define SS 128
#define EPS_ 1e-6f
#define NTHREADS 1024
#define NK 12          // u_0..u_12; deg-12 tail at typ c~2.1: ~3e-6 rel
#define SX 65          // bX row stride in floats (odd mod 32 -> bank-spread rows)

typedef __attribute__((ext_vector_type(8))) short bf16x8;
typedef __attribute__((ext_vector_type(4))) float f32x4;

__device__ __forceinline__ unsigned short f2bf(float f) {
    unsigned u = __float_as_uint(f);
    unsigned r = u + 0x7FFFu + ((u >> 16) & 1u);   // round-to-nearest-even
    return (unsigned short)(r >> 16);
}
__device__ __forceinline__ float bf2f(unsigned short h) {
    return __uint_as_float(((unsigned)h) << 16);
}
// broadcast lane c of v to all lanes (compile-time c)
__device__ __forceinline__ float rdlane(float v, int c) {
    return __uint_as_float(__builtin_amdgcn_readlane(__float_as_uint(v), c));
}
// swizzled element index in a [64][64] bf16 matrix: 8-elem k-blocks contiguous,
// block index XORed with (row&7) so cross-row access spreads across banks
__device__ __forceinline__ int SWZ(int r, int c) {
    return r * 64 + ((((c & ~7) ^ ((r & 7) << 3))) | (c & 7));
}
// 8 contiguous bf16 of row `row`, k-block k0 (multiple of 8)
__device__ __forceinline__ bf16x8 ldrow(const short* m, int row, int k0) {
    return *(const bf16x8*)&m[row * 64 + (k0 ^ ((row & 7) << 3))];
}

#define MFMA(a, b, c) __builtin_amdgcn_mfma_f32_16x16x32_bf16((a), (b), (c), 0, 0, 0)

__launch_bounds__(NTHREADS, 4)   // 4 waves/EU -> 128 VGPR budget: xr[64] provably fits
__global__ void htg_kernel(const float* __restrict__ z0,
                           const float* __restrict__ time_steps,
                           const float* __restrict__ k_coeffs,
                           const float* __restrict__ r_coeffs,
                           const float* __restrict__ alpha_p,
                           const float* __restrict__ beta_p,
                           const float* __restrict__ K_bases,
                           const float* __restrict__ R_bases,
                           float* __restrict__ out,
                           int interleaved)
{
    __shared__ float bK[DD * DD];        // Ksum fp32, elem-XOR layout
    __shared__ short rtH[DD * DD];       // Rsum^T bf16 high (SWZ rows)
    __shared__ short rtL[DD * DD];       // Rsum^T bf16 low residual
    __shared__ float bX[DD * SX];        // X fp32, stride-65 rows
    __shared__ float us[NK + 1][DD];     // Krylov vectors u_k = X^k z0

    const int tid = threadIdx.x;
    const int b   = blockIdx.x;          // batch
    const int wv  = tid >> 6;            // wave 0..15 -> 16x16 tile (tr, tc)
    const int l   = tid & 63;
    const int tr  = wv >> 2, tc = wv & 3;
    const int q   = l >> 4;              // k-subgroup 0..3
    const int cl  = l & 15;

    const float alpha = alpha_p[b];
    const float beta  = beta_p[b];
    const float dt    = time_steps[0];   // uniform grid
    float kc[NN], rc[NN];
#pragma unroll
    for (int n = 0; n < NN; ++n) {
        kc[n] = k_coeffs[b * NN + n];
        rc[n] = r_coeffs[b * NN + n];
    }
    float zv = 0.f;
    if (wv == 0) zv = z0[b * DD + l];    // latency hides under Phase A

    // ---- Phase A: Ksum fp32 (elem-XOR) -> bK; Rsum^T split-bf16 (SWZ rows) -> rtH/rtL ----
    {
        const int i  = tid >> 4;
        const int j0 = (tid & 15) * 4;
        const int e4 = i * DD + j0;
        float4 ks = make_float4(0.f, 0.f, 0.f, 0.f);
        float4 rs = make_float4(0.f, 0.f, 0.f, 0.f);
#pragma unroll
        for (int n = 0; n < NN; ++n) {
            float4 kb = *(const float4*)&K_bases[n * DD * DD + e4];
            float4 rb = *(const float4*)&R_bases[n * DD * DD + e4];
            ks.x = fmaf(kc[n], kb.x, ks.x); ks.y = fmaf(kc[n], kb.y, ks.y);
            ks.z = fmaf(kc[n], kb.z, ks.z); ks.w = fmaf(kc[n], kb.w, ks.w);
            rs.x = fmaf(rc[n], rb.x, rs.x); rs.y = fmaf(rc[n], rb.y, rs.y);
            rs.z = fmaf(rc[n], rb.z, rs.z); rs.w = fmaf(rc[n], rb.w, rs.w);
        }
        const int c = i & 31;
        bK[i * DD + ((j0 + 0) ^ c)] = ks.x;
        bK[i * DD + ((j0 + 1) ^ c)] = ks.y;
        bK[i * DD + ((j0 + 2) ^ c)] = ks.z;
        bK[i * DD + ((j0 + 3) ^ c)] = ks.w;
        // transposed store: value (i, j0+t) -> RT[j0+t][i]
        float rv[4] = {rs.x, rs.y, rs.z, rs.w};
#pragma unroll
        for (int t = 0; t < 4; ++t) {
            unsigned short h  = f2bf(rv[t]);
            unsigned short lo = f2bf(rv[t] - bf2f(h));
            const int a = SWZ(j0 + t, i);
            rtH[a] = (short)h; rtL[a] = (short)lo;
        }
    }
    __syncthreads();

    // ---- MM1 (MFMA): RtR[i][j] = sum_k RT[i][k]*RT[j][k]; all fragments b128 row reads.
    //      X = dt*(alpha*(K-K^T) - beta*RtR) + eps*I -> bX fp32 (stride 65) ----
    {
        f32x4 accR = {0.f, 0.f, 0.f, 0.f};
        const int rowA = 16 * tr + cl;
        const int rowB = 16 * tc + cl;   // B[k][j] = RT[j][k] -> row j of RT
#pragma unroll
        for (int hK = 0; hK < 2; ++hK) {
            const int k0 = 32 * hK + 8 * q;
            bf16x8 aH = ldrow(rtH, rowA, k0), aL = ldrow(rtL, rowA, k0);
            bf16x8 bH = ldrow(rtH, rowB, k0), bL = ldrow(rtL, rowB, k0);
            accR = MFMA(aH, bH, accR);
            accR = MFMA(aH, bL, accR);
            accR = MFMA(aL, bH, accR);
        }
#pragma unroll
        for (int r = 0; r < 4; ++r) {
            const int i = 16 * tr + 4 * q + r;
            const int j = 16 * tc + cl;
            const float kij = bK[i * DD + (j ^ (i & 31))];
            const float kji = bK[j * DD + (i ^ (j & 31))];
            float x = dt * (alpha * (kij - kji) - beta * accR[r]);
            if (i == j) x += EPS_;
            bX[i * SX + j] = x;
        }
    }
    __syncthreads();

    // ---- Chain (wave 0 only, register-resident): u_k = X*u_{k-1} via readlane broadcast ----
    if (wv == 0) {
        float xr[DD];                    // row l of X (compile-time indexed; 128-VGPR budget)
#pragma unroll
        for (int c = 0; c < DD; c += 4) {
            float4 t4 = *(const float4*)&bX[l * SX + c];
            xr[c + 0] = t4.x; xr[c + 1] = t4.y; xr[c + 2] = t4.z; xr[c + 3] = t4.w;
        }
        float u = zv;
        us[0][l] = zv;
        for (int k = 1; k <= NK; ++k) {
            float a0 = 0.f, a1 = 0.f, a2 = 0.f, a3 = 0.f;
#pragma unroll
            for (int c = 0; c < DD; c += 4) {
                a0 = fmaf(xr[c + 0], rdlane(u, c + 0), a0);
                a1 = fmaf(xr[c + 1], rdlane(u, c + 1), a1);
                a2 = fmaf(xr[c + 2], rdlane(u, c + 2), a2);
                a3 = fmaf(xr[c + 3], rdlane(u, c + 3), a3);
            }
            u = (a0 + a1) + (a2 + a3);
            us[k][l] = u;                // write-and-forget; consumed after barrier
        }
    }
    __syncthreads();

    // ---- Output (Horner): z_s[i] = sum_k t^k * (u_k[i]/k!), t = s+1 ----
    {
        const int i  = tid & 63;
        const int sb = tid >> 6;         // 0..15
        const float INVF[NK + 1] = {
            1.f, 1.f, 0.5f, 1.66666667e-1f, 4.16666667e-2f, 8.33333333e-3f,
            1.38888889e-3f, 1.98412698e-4f, 2.48015873e-5f, 2.75573192e-6f,
            2.75573192e-7f, 2.50521084e-8f, 2.08767570e-9f };
        float w[NK + 1];
#pragma unroll
        for (int k = 0; k <= NK; ++k) w[k] = us[k][i] * INVF[k];
#pragma unroll
        for (int r = 0; r < 8; ++r) {
            const int s = sb + 16 * r;
            const float t = (float)(s + 1);
            float acc = w[NK];
#pragma unroll
            for (int k = NK - 1; k >= 0; --k) acc = fmaf(acc, t, w[k]);
            const size_t oi = ((size_t)(b * SS + s)) * DD + i;
            if (interleaved) ((float2*)out)[oi] = make_float2(acc, 0.f);
            else             out[oi] = acc;
        }
    }
}

extern "C" void kernel_launch(void* const* d_in, const int* in_sizes, int n_in,
                              void* d_out, int out_size, void* d_ws, size_t ws_size,
                              hipStream_t stream) {
    const float* z0         = (const float*)d_in[0];
    const float* time_steps = (const float*)d_in[1];
    const float* k_coeffs   = (const float*)d_in[2];
    const float* r_coeffs   = (const float*)d_in[3];
    const float* alpha      = (const float*)d_in[4];
    const float* beta       = (const float*)d_in[5];
    const float* K_bases    = (const float*)d_in[6];
    const float* R_bases    = (const float*)d_in[7];
    float* out = (float*)d_out;

    const int n_z = BATCH * SS * DD;
    const int interleaved = (out_size >= 2 * n_z) ? 1 : 0;

    htg_kernel<<<dim3(BATCH), dim3(NTHREADS), 0, stream>>>(
        z0, time_steps, k_coeffs, r_coeffs, alpha, beta, K_bases, R_bases,
        out, interleaved);
}

// Round 14
// 12.667 us; speedup vs baseline: 2.0084x; 1.0238x over previous
//
#include <hip/hip_runtime.h>

#define BATCH 32
#define DD 64
#define NN 8
#define SS 128
#define EPS_ 1e-6f
#define NTHREADS 1024
#define NK 11          // u_1..u_11; deg-11 tail at worst c~2.8: 2.8^12/12! ~ 4.8e-4 rel
#define SX 65          // bX row stride in floats (odd mod 32 -> bank-spread rows)

typedef __attribute__((ext_vector_type(8))) short bf16x8;
typedef __attribute__((ext_vector_type(4))) float f32x4;

__device__ __forceinline__ unsigned short f2bf(float f) {
    unsigned u = __float_as_uint(f);
    unsigned r = u + 0x7FFFu + ((u >> 16) & 1u);   // round-to-nearest-even
    return (unsigned short)(r >> 16);
}
__device__ __forceinline__ float bf2f(unsigned short h) {
    return __uint_as_float(((unsigned)h) << 16);
}
// broadcast lane c of v to all lanes (compile-time c)
__device__ __forceinline__ float rdlane(float v, int c) {
    return __uint_as_float(__builtin_amdgcn_readlane(__float_as_uint(v), c));
}
// swizzled element index in a [64][64] bf16 matrix: 8-elem k-blocks contiguous,
// block index XORed with (row&7) so cross-row access spreads across banks
__device__ __forceinline__ int SWZ(int r, int c) {
    return r * 64 + ((((c & ~7) ^ ((r & 7) << 3))) | (c & 7));
}
// 8 contiguous bf16 of row `row`, k-block k0 (multiple of 8)
__device__ __forceinline__ bf16x8 ldrow(const short* m, int row, int k0) {
    return *(const bf16x8*)&m[row * 64 + (k0 ^ ((row & 7) << 3))];
}

#define MFMA(a, b, c) __builtin_amdgcn_mfma_f32_16x16x32_bf16((a), (b), (c), 0, 0, 0)

__launch_bounds__(NTHREADS, 4)   // 4 waves/EU -> 128 VGPR budget: xr[64] fits, no spill
__global__ void htg_kernel(const float* __restrict__ z0,
                           const float* __restrict__ time_steps,
                           const float* __restrict__ k_coeffs,
                           const float* __restrict__ r_coeffs,
                           const float* __restrict__ alpha_p,
                           const float* __restrict__ beta_p,
                           const float* __restrict__ K_bases,
                           const float* __restrict__ R_bases,
                           float* __restrict__ out,
                           int interleaved)
{
    __shared__ float bK[DD * DD];        // Ksum fp32, elem-XOR layout
    __shared__ short rtH[DD * DD];       // Rsum^T bf16 high (SWZ rows)
    __shared__ short rtL[DD * DD];       // Rsum^T bf16 low residual
    __shared__ float bX[DD * SX];        // X fp32, stride-65 rows
    __shared__ float us[NK + 1][DD];     // Krylov vectors u_k = X^k z0 (index 0 unused)

    const int tid = threadIdx.x;
    const int b   = blockIdx.x;          // batch
    const int wv  = tid >> 6;            // wave 0..15 -> 16x16 tile (tr, tc)
    const int l   = tid & 63;
    const int tr  = wv >> 2, tc = wv & 3;
    const int q   = l >> 4;              // k-subgroup 0..3
    const int cl  = l & 15;

    const float alpha = alpha_p[b];
    const float beta  = beta_p[b];
    const float dt    = time_steps[0];   // uniform grid
    float kc[NN], rc[NN];
#pragma unroll
    for (int n = 0; n < NN; ++n) {
        kc[n] = k_coeffs[b * NN + n];
        rc[n] = r_coeffs[b * NN + n];
    }
    float zv = 0.f;
    if (wv == 0) zv = z0[b * DD + l];    // latency hides under Phase A

    // ---- Phase A: Ksum fp32 (elem-XOR) -> bK; Rsum^T split-bf16 (SWZ rows) -> rtH/rtL ----
    {
        const int i  = tid >> 4;
        const int j0 = (tid & 15) * 4;
        const int e4 = i * DD + j0;
        float4 ks = make_float4(0.f, 0.f, 0.f, 0.f);
        float4 rs = make_float4(0.f, 0.f, 0.f, 0.f);
#pragma unroll
        for (int n = 0; n < NN; ++n) {
            float4 kb = *(const float4*)&K_bases[n * DD * DD + e4];
            float4 rb = *(const float4*)&R_bases[n * DD * DD + e4];
            ks.x = fmaf(kc[n], kb.x, ks.x); ks.y = fmaf(kc[n], kb.y, ks.y);
            ks.z = fmaf(kc[n], kb.z, ks.z); ks.w = fmaf(kc[n], kb.w, ks.w);
            rs.x = fmaf(rc[n], rb.x, rs.x); rs.y = fmaf(rc[n], rb.y, rs.y);
            rs.z = fmaf(rc[n], rb.z, rs.z); rs.w = fmaf(rc[n], rb.w, rs.w);
        }
        const int c = i & 31;
        bK[i * DD + ((j0 + 0) ^ c)] = ks.x;
        bK[i * DD + ((j0 + 1) ^ c)] = ks.y;
        bK[i * DD + ((j0 + 2) ^ c)] = ks.z;
        bK[i * DD + ((j0 + 3) ^ c)] = ks.w;
        // transposed store: value (i, j0+t) -> RT[j0+t][i]
        float rv[4] = {rs.x, rs.y, rs.z, rs.w};
#pragma unroll
        for (int t = 0; t < 4; ++t) {
            unsigned short h  = f2bf(rv[t]);
            unsigned short lo = f2bf(rv[t] - bf2f(h));
            const int a = SWZ(j0 + t, i);
            rtH[a] = (short)h; rtL[a] = (short)lo;
        }
    }
    __syncthreads();

    // ---- MM1 (MFMA): RtR[i][j] = sum_k RT[i][k]*RT[j][k]; all fragments b128 row reads.
    //      X = dt*(alpha*(K-K^T) - beta*RtR) + eps*I -> bX fp32 (stride 65) ----
    {
        f32x4 accR = {0.f, 0.f, 0.f, 0.f};
        const int rowA = 16 * tr + cl;
        const int rowB = 16 * tc + cl;   // B[k][j] = RT[j][k] -> row j of RT
#pragma unroll
        for (int hK = 0; hK < 2; ++hK) {
            const int k0 = 32 * hK + 8 * q;
            bf16x8 aH = ldrow(rtH, rowA, k0), aL = ldrow(rtL, rowA, k0);
            bf16x8 bH = ldrow(rtH, rowB, k0), bL = ldrow(rtL, rowB, k0);
            accR = MFMA(aH, bH, accR);
            accR = MFMA(aH, bL, accR);
            accR = MFMA(aL, bH, accR);
        }
#pragma unroll
        for (int r = 0; r < 4; ++r) {
            const int i = 16 * tr + 4 * q + r;
            const int j = 16 * tc + cl;
            const float kij = bK[i * DD + (j ^ (i & 31))];
            const float kji = bK[j * DD + (i ^ (j & 31))];
            float x = dt * (alpha * (kij - kji) - beta * accR[r]);
            if (i == j) x += EPS_;
            bX[i * SX + j] = x;
        }
    }
    __syncthreads();

    // ---- Chain (wave 0 only, register-resident): u_k = X*u_{k-1} via readlane broadcast ----
    if (wv == 0) {
        float xr[DD];                    // row l of X (compile-time indexed)
#pragma unroll
        for (int c = 0; c < DD; c += 4) {
            float4 t4 = *(const float4*)&bX[l * SX + c];
            xr[c + 0] = t4.x; xr[c + 1] = t4.y; xr[c + 2] = t4.z; xr[c + 3] = t4.w;
        }
        float u = zv;
        for (int k = 1; k <= NK; ++k) {
            float a0 = 0.f, a1 = 0.f, a2 = 0.f, a3 = 0.f;
#pragma unroll
            for (int c = 0; c < DD; c += 4) {
                a0 = fmaf(xr[c + 0], rdlane(u, c + 0), a0);
                a1 = fmaf(xr[c + 1], rdlane(u, c + 1), a1);
                a2 = fmaf(xr[c + 2], rdlane(u, c + 2), a2);
                a3 = fmaf(xr[c + 3], rdlane(u, c + 3), a3);
            }
            u = (a0 + a1) + (a2 + a3);
            us[k][l] = u;                // write-and-forget; consumed after barrier
        }
    }
    __syncthreads();

    // ---- Output (Horner): z_s[i] = u0[i] + sum_{k>=1} t^k * (u_k[i]/k!), t = s+1 ----
    {
        const int i  = tid & 63;
        const int sb = tid >> 6;         // 0..15
        const float INVF[NK + 1] = {
            1.f, 1.f, 0.5f, 1.66666667e-1f, 4.16666667e-2f, 8.33333333e-3f,
            1.38888889e-3f, 1.98412698e-4f, 2.48015873e-5f, 2.75573192e-6f,
            2.75573192e-7f, 2.50521084e-8f };
        float w[NK + 1];
        w[0] = z0[b * DD + i];           // direct global read (L2-hot), no LDS round-trip
#pragma unroll
        for (int k = 1; k <= NK; ++k) w[k] = us[k][i] * INVF[k];
#pragma unroll
        for (int r = 0; r < 8; ++r) {
            const int s = sb + 16 * r;
            const float t = (float)(s + 1);
            float acc = w[NK];
#pragma unroll
            for (int k = NK - 1; k >= 0; --k) acc = fmaf(acc, t, w[k]);
            const size_t oi = ((size_t)(b * SS + s)) * DD + i;
            if (interleaved) ((float2*)out)[oi] = make_float2(acc, 0.f);
            else             out[oi] = acc;
        }
    }
}

extern "C" void kernel_launch(void* const* d_in, const int* in_sizes, int n_in,
                              void* d_out, int out_size, void* d_ws, size_t ws_size,
                              hipStream_t stream) {
    const float* z0         = (const float*)d_in[0];
    const float* time_steps = (const float*)d_in[1];
    const float* k_coeffs   = (const float*)d_in[2];
    const float* r_coeffs   = (const float*)d_in[3];
    const float* alpha      = (const float*)d_in[4];
    const float* beta       = (const float*)d_in[5];
    const float* K_bases    = (const float*)d_in[6];
    const float* R_bases    = (const float*)d_in[7];
    float* out = (float*)d_out;

    const int n_z = BATCH * SS * DD;
    const int interleaved = (out_size >= 2 * n_z) ? 1 : 0;

    htg_kernel<<<dim3(BATCH), dim3(NTHREADS), 0, stream>>>(
        z0, time_steps, k_coeffs, r_coeffs, alpha, beta, K_bases, R_bases,
        out, interleaved);
}